// Round 9
// baseline (160.034 us; speedup 1.0000x reference)
//
#include <hip/hip_runtime.h>
#include <hip/hip_bf16.h>

typedef __hip_bfloat16 bf16;
typedef __attribute__((ext_vector_type(8))) short bf16x8;   // 8 bf16 = 4 VGPRs (MFMA A/B frag)
typedef __attribute__((ext_vector_type(4))) float f32x4;    // MFMA C/D frag
typedef __attribute__((ext_vector_type(2))) unsigned int u32x2;

#define MFMA(a, b, c) __builtin_amdgcn_mfma_f32_16x16x32_bf16((a), (b), (c), 0, 0, 0)

static __device__ __forceinline__ float bf2f(bf16 b) { return __bfloat162float(b); }

// Packed f32->bf16 (truncation) via single v_perm_b32 (passed r7/r8).
static __device__ __forceinline__ unsigned pk2(float a, float b) {
    return __builtin_amdgcn_perm(__builtin_bit_cast(unsigned, b),
                                 __builtin_bit_cast(unsigned, a), 0x07060302u);
}

// Async global->LDS DMA, 16B per lane. LDS dest = uniform base + lane*16.
static __device__ __forceinline__ void gload16(const void* g, void* l) {
    __builtin_amdgcn_global_load_lds(
        (const __attribute__((address_space(1))) void*)g,
        (__attribute__((address_space(3))) void*)l, 16, 0, 0);
}

static __device__ __forceinline__ float quad_max(float x) {
    x = fmaxf(x, __shfl_xor(x, 16));
    x = fmaxf(x, __shfl_xor(x, 32));
    return x;
}
static __device__ __forceinline__ float quad_sum(float x) {
    x += __shfl_xor(x, 16);
    x += __shfl_xor(x, 32);
    return x;
}

// ---------------------------------------------------------------------------
// Phase 0a: convert hidden_states (4096x1024) and dist_emb (4095x64) to bf16
// ---------------------------------------------------------------------------
__global__ void prep_convert(const float* __restrict__ X, const float* __restrict__ DE,
                             bf16* __restrict__ Xb, bf16* __restrict__ DEb) {
    int i = blockIdx.x * blockDim.x + threadIdx.x;
    if (i < 1048576) {
        float4 v = reinterpret_cast<const float4*>(X)[i];
        bf16* d = Xb + 4 * i;
        d[0] = __float2bfloat16(v.x); d[1] = __float2bfloat16(v.y);
        d[2] = __float2bfloat16(v.z); d[3] = __float2bfloat16(v.w);
    } else {
        int j = i - 1048576;
        if (j < 65520) {
            float4 v = reinterpret_cast<const float4*>(DE)[j];
            bf16* d = DEb + 4 * j;
            d[0] = __float2bfloat16(v.x); d[1] = __float2bfloat16(v.y);
            d[2] = __float2bfloat16(v.z); d[3] = __float2bfloat16(v.w);
        }
    }
}

// ---------------------------------------------------------------------------
// Phase 0b: transpose Wq/Wk/Wv (1024x1024 f32, [in][out]) -> WT bf16 [out][in]
// ---------------------------------------------------------------------------
__global__ void prep_transpose_w(const float* __restrict__ Wq, const float* __restrict__ Wk,
                                 const float* __restrict__ Wv, bf16* __restrict__ WTb) {
    const float* W = (blockIdx.z == 0) ? Wq : (blockIdx.z == 1) ? Wk : Wv;
    bf16* WT = WTb + (size_t)blockIdx.z * (1024u * 1024u);
    __shared__ float t[64][65];
    int tid = threadIdx.x;
    int col = tid & 63;
    int r4 = tid >> 6;
    int i0 = blockIdx.x * 64, o0 = blockIdx.y * 64;
    for (int it = 0; it < 16; ++it) {
        int row = it * 4 + r4;
        t[row][col] = W[(size_t)(i0 + row) * 1024 + o0 + col];
    }
    __syncthreads();
    for (int it = 0; it < 16; ++it) {
        int row = it * 4 + r4;
        WT[(size_t)(o0 + row) * 1024 + i0 + col] = __float2bfloat16(t[col][row]);
    }
}

// ---------------------------------------------------------------------------
// Phase 1: QKV projection GEMM (unchanged — passed).
// ---------------------------------------------------------------------------
__global__ __launch_bounds__(256, 2) void proj_gemm(
    const bf16* __restrict__ Xb, const bf16* __restrict__ WTb,
    const float* __restrict__ bq, const float* __restrict__ bk, const float* __restrict__ bv,
    bf16* __restrict__ Qb, bf16* __restrict__ Kb, bf16* __restrict__ VTb) {
    int proj = blockIdx.z;
    const bf16* W = WTb + (size_t)proj * (1024u * 1024u);
    const float* bias = (proj == 0) ? bq : (proj == 1) ? bk : bv;

    __shared__ bf16 XT[128][72];
    __shared__ bf16 WTt[128][72];

    int tid = threadIdx.x;
    int w = tid >> 6, lane = tid & 63, g = lane >> 4, li = lane & 15;
    int wr = w >> 1, wc = w & 1;
    int m0 = blockIdx.x * 128, n0 = blockIdx.y * 128;

    f32x4 acc[4][4];
    for (int mt = 0; mt < 4; mt++)
        for (int nt = 0; nt < 4; nt++) acc[mt][nt] = {0.f, 0.f, 0.f, 0.f};

    for (int ks = 0; ks < 16; ++ks) {
        for (int it = 0; it < 4; ++it) {
            int idx = tid + 256 * it;
            int row = idx >> 3, c = (idx & 7) * 8;
            *reinterpret_cast<bf16x8*>(&XT[row][c]) =
                *reinterpret_cast<const bf16x8*>(Xb + (size_t)(m0 + row) * 1024 + ks * 64 + c);
            *reinterpret_cast<bf16x8*>(&WTt[row][c]) =
                *reinterpret_cast<const bf16x8*>(W + (size_t)(n0 + row) * 1024 + ks * 64 + c);
        }
        __syncthreads();
        for (int kk = 0; kk < 2; ++kk) {
            bf16x8 af[4], bfr[4];
            for (int mt = 0; mt < 4; mt++)
                af[mt] = *reinterpret_cast<const bf16x8*>(&XT[64 * wr + 16 * mt + li][32 * kk + 8 * g]);
            for (int nt = 0; nt < 4; nt++)
                bfr[nt] = *reinterpret_cast<const bf16x8*>(&WTt[64 * wc + 16 * nt + li][32 * kk + 8 * g]);
            for (int mt = 0; mt < 4; mt++)
                for (int nt = 0; nt < 4; nt++)
                    acc[mt][nt] = MFMA(af[mt], bfr[nt], acc[mt][nt]);
        }
        __syncthreads();
    }

    for (int mt = 0; mt < 4; mt++)
        for (int nt = 0; nt < 4; nt++) {
            int n = n0 + 64 * wc + 16 * nt + li;
            int h = n >> 6, d = n & 63;
            float bv_ = bias[n];
            for (int r = 0; r < 4; r++) {
                int m = m0 + 64 * wr + 16 * mt + 4 * g + r;
                int b = m >> 10, s = m & 1023;
                bf16 o = __float2bfloat16(acc[mt][nt][r] + bv_);
                if (proj == 0)      Qb[((size_t)(b * 16 + h) * 1024 + s) * 64 + d] = o;
                else if (proj == 1) Kb[((size_t)(b * 16 + h) * 1024 + s) * 64 + d] = o;
                else                VTb[((size_t)(b * 16 + h) * 64 + d) * 1024 + s] = o;
            }
        }
}

// ---------------------------------------------------------------------------
// Phase 2: fused attention v9 — r8 structure on a 53.76KB LDS diet:
// VT single-buffered (V-DMA at loop top), P overlaid on per-wave QD region,
// QD/KD pitch 160. 3 blocks/CU.
// ---------------------------------------------------------------------------
__global__ __launch_bounds__(256, 3) void attn_fused(
    const bf16* __restrict__ Qg, const bf16* __restrict__ Kg,
    const bf16* __restrict__ VTg, const bf16* __restrict__ DEb,
    const float* __restrict__ mask, float* __restrict__ out) {
    const int S = 1024, D = 64;
    const float C8 = 0.18033688011112042f;   // log2(e)/8
    int p_ = blockIdx.x;
    int bh = (p_ & 7) * 8 + ((p_ >> 3) >> 4);
    int qb = (p_ >> 3) & 15;
    int b = bh >> 4, h = bh & 15;
    int L0 = qb * 64;

    int tid = threadIdx.x;
    int w = tid >> 6, lane = tid & 63, g = lane >> 4, li = lane & 15;

    // LDS layout (53760 B):
    //  K   [64][128B]  linear+swz  @ 0      (8192)
    //  VT  [64][128B]  linear+swz  @ 8192   (8192)   single buffer
    //  DE  [128][128B] linear+swz  @ 16384  (16384, circular halves)
    //  QD  [4][16 rows x 160B]     @ 32768  (10240)  (P overlays per-wave)
    //  KD  [64 rows x 160B]        @ 43008  (10240)
    //  M   [2][64] f32             @ 53248  (512)
    __shared__ __align__(16) char smem[53760];
    float (*M_lds)[64] = reinterpret_cast<float(*)[64]>(smem + 53248);

    const bf16* Qh = Qg + (size_t)bh * S * D;
    const bf16* Kh = Kg + (size_t)bh * S * D;
    const bf16* Vh = VTg + (size_t)bh * D * S;
    const float* maskb = mask + (size_t)b * S;

    // ---- lane-constant swizzled read bases ----
    int sw = (li & 7) << 4;
    int c0 = (16 * g) ^ sw;          // k-slice 0 (bytes 0..63 of row)
    int c1 = (64 + 16 * g) ^ sw;     // k-slice 1 (bytes 64..127)
    const char* KbL = smem + li * 128;              // + nt*2048 + c0/c1
    const char* KaL = smem + (16 * (3 - w) + li) * 128;
    const char* Vb_ = smem + 8192 + li * 128;       // + dt*2048 + c
    const char* Db_ = smem + 16384;                 // + dr*128 + c

    // ---- stager constants (per-lane source swizzle, linear dest) ----
    int cr = lane >> 3;                    // chunk row 0..7
    int sc = 16 * ((lane & 7) ^ cr);       // swizzled source col byte

    // Q frags (B-operand: col li <-> Q row 16w+li)
    bf16x8 qa0, qa1;
    {
        const bf16* qrow = Qh + (size_t)(L0 + 16 * w + li) * D;
        qa0 = *reinterpret_cast<const bf16x8*>(qrow + 8 * g);
        qa1 = *reinterpret_cast<const bf16x8*>(qrow + 32 + 8 * g);
    }

    // kt-invariant QD/KD/P pointers (pitch 160; P overlays QD[w])
    const char* qdb = smem + 32768 + 2560 * w + 162 * li - 8 * g;  // + (126-32nt-2r)
    const char* kdb = smem + 43008 + 632 * g + 32 * w + 2 * li + 30; // + 2560nt+158r
    char* qsp = smem + 32768 + 2560 * w + 160 * li + 8 * g;        // + 32jt
    char* ksp = smem + 43008 + 160 * (48 - 16 * w + li) + 8 * g;   // + 32jt
    char* Pp  = smem + 32768 + 2560 * w + 144 * li;                // overlay

    // ---- Prologue: DMA K(0), VT(0), DE window [de00,de00+128), mask(0) ----
    int de00 = L0 + 1984;
    {
        #pragma unroll
        for (int i = 0; i < 2; ++i) {
            int blk = w * 2 + i;
            int row = blk * 8 + cr;
            gload16((const char*)Kh + (size_t)row * 128 + sc, smem + blk * 1024);
            gload16((const char*)Vh + (size_t)row * 2048 + sc, smem + 8192 + blk * 1024);
        }
        #pragma unroll
        for (int i = 0; i < 4; ++i) {
            int blk = w * 4 + i;
            int row = blk * 8 + cr;                          // 0..127
            int ldsoff = (((de00 & 64) * 128) + blk * 1024) & 16383;
            gload16((const char*)DEb + (size_t)(de00 + row) * 128 + sc, smem + 16384 + ldsoff);
        }
        if (tid < 64) M_lds[0][tid] = maskb[tid];
    }

    f32x4 acc_o[4];
    for (int dt = 0; dt < 4; dt++) acc_o[dt] = {0.f, 0.f, 0.f, 0.f};
    float m_run = -1e30f, l_run = 0.f;

    __syncthreads();   // drains DMA (vmcnt) + mask write

    for (int kt = 0; kt < 16; ++kt) {
        int r0 = kt * 64;
        int de0 = de00 - r0;
        bool has_next = (kt < 15);

        // ---- V(kt) DMA (kt>0): VT reads of kt-1 done at barrier2; lands
        //      during Phase B, drained by barrier1, read in Phase C ----
        if (kt) {
            #pragma unroll
            for (int i = 0; i < 2; ++i) {
                int blk = w * 2 + i;
                int row = blk * 8 + cr;
                gload16((const char*)Vh + (size_t)row * 2048 + (size_t)r0 * 2 + sc,
                        smem + 8192 + blk * 1024);
            }
        }

        // ---- Phase B: swapped QK^T + QD/KD production (swizzled reads) ----
        __builtin_amdgcn_s_setprio(1);
        f32x4 s_acc[4];
        #pragma unroll
        for (int nt = 0; nt < 4; ++nt) {
            bf16x8 kb0 = *reinterpret_cast<const bf16x8*>(KbL + nt * 2048 + c0);
            bf16x8 kb1 = *reinterpret_cast<const bf16x8*>(KbL + nt * 2048 + c1);
            f32x4 z = {0.f, 0.f, 0.f, 0.f};
            z = MFMA(kb0, qa0, z);     // S^T[k=16nt+4g+r][q=16w+li]
            z = MFMA(kb1, qa1, z);
            s_acc[nt] = z;
        }
        {
            bf16x8 ka0 = *reinterpret_cast<const bf16x8*>(KaL + c0);
            bf16x8 ka1 = *reinterpret_cast<const bf16x8*>(KaL + c1);
            #pragma unroll
            for (int jt = 0; jt < 5; ++jt) {
                int dr = (de0 + 16 * w + 16 * jt + li) & 127;
                bf16x8 d0 = *reinterpret_cast<const bf16x8*>(Db_ + dr * 128 + c0);
                bf16x8 d1 = *reinterpret_cast<const bf16x8*>(Db_ + dr * 128 + c1);
                f32x4 aq = {0.f, 0.f, 0.f, 0.f};
                aq = MFMA(d0, qa0, aq);    // QD^T[jrel][q]
                aq = MFMA(d1, qa1, aq);
                f32x4 ak = {0.f, 0.f, 0.f, 0.f};
                ak = MFMA(d0, ka0, ak);    // KD^T[jrel][k=16(3-w)+li]
                ak = MFMA(d1, ka1, ak);
                u32x2 uq = {pk2(aq[0], aq[1]), pk2(aq[2], aq[3])};
                *reinterpret_cast<u32x2*>(qsp + 32 * jt) = uq;
                u32x2 uk = {pk2(ak[0], ak[1]), pk2(ak[2], ak[3])};
                *reinterpret_cast<u32x2*>(ksp + 32 * jt) = uk;
            }
        }
        __builtin_amdgcn_s_setprio(0);
        __syncthreads();   // QD/KD visible; K/DE reads done; V(kt) landed

        // ---- issue next-tile K/DE DMAs (fly under Phase C, drain barrier2) ----
        float sM;
        if (has_next) {
            int r0n = r0 + 64;
            int dlo = de0 - 64;
            #pragma unroll
            for (int i = 0; i < 2; ++i) {
                int blk = w * 2 + i;
                int row = blk * 8 + cr;
                gload16((const char*)Kh + (size_t)(r0n + row) * 128 + sc, smem + blk * 1024);
                gload16((const char*)DEb + (size_t)(dlo + row) * 128 + sc,
                        smem + 16384 + (dlo & 64) * 128 + blk * 1024);
            }
            if (tid < 64) sM = maskb[r0n + tid];
        }

        // ---- Phase C: gather + bias + lane-local softmax (scale folded) ----
        float u[4][4];
        float lmax = -1e30f;
        #pragma unroll
        for (int nt = 0; nt < 4; ++nt) {
            f32x4 mk4 = *reinterpret_cast<const f32x4*>(&M_lds[kt & 1][16 * nt + 4 * g]);
            #pragma unroll
            for (int r = 0; r < 4; ++r) {
                float qd = bf2f(*reinterpret_cast<const bf16*>(qdb + (126 - 32 * nt - 2 * r)));
                float kd = bf2f(*reinterpret_cast<const bf16*>(kdb + (2560 * nt + 158 * r)));
                float uu = s_acc[nt][r] + qd + kd;
                uu = __builtin_fmaf(mk4[r], 8.0f, uu);
                u[nt][r] = uu;
                lmax = fmaxf(lmax, uu);
            }
        }
        float tm = quad_max(lmax);
        bool noskip = !__all(tm <= m_run);
        float scl = 1.0f;
        if (noskip) {
            float mnew = fmaxf(m_run, tm);
            scl = exp2f((m_run - mnew) * C8);
            m_run = mnew;
        }
        float nmc = -m_run * C8;
        float pv[4][4];
        #pragma unroll
        for (int nt = 0; nt < 4; ++nt)
            #pragma unroll
            for (int r = 0; r < 4; ++r)
                pv[nt][r] = exp2f(__builtin_fmaf(u[nt][r], C8, nmc));
        float t0 = (pv[0][0] + pv[0][1]) + (pv[0][2] + pv[0][3]);
        float t1 = (pv[1][0] + pv[1][1]) + (pv[1][2] + pv[1][3]);
        float t2 = (pv[2][0] + pv[2][1]) + (pv[2][2] + pv[2][3]);
        float t3 = (pv[3][0] + pv[3][1]) + (pv[3][2] + pv[3][3]);
        float qs = quad_sum((t0 + t1) + (t2 + t3));
        if (noskip) {
            l_run = l_run * scl + qs;
            #pragma unroll
            for (int dt = 0; dt < 4; dt++) acc_o[dt] *= scl;
        } else {
            l_run += qs;
        }

        // ---- P^T -> wave-private LDS (overlay on QD[w]; all QD gathers of
        //      this wave precede these writes in program order) ----
        #pragma unroll
        for (int nt = 0; nt < 4; ++nt) {
            u32x2 pp = {pk2(pv[nt][0], pv[nt][1]), pk2(pv[nt][2], pv[nt][3])};
            *reinterpret_cast<u32x2*>(Pp + 32 * nt + 8 * g) = pp;
        }
        bf16x8 pb0 = *reinterpret_cast<const bf16x8*>(Pp + 16 * g);        // k=8g..8g+7
        bf16x8 pb1 = *reinterpret_cast<const bf16x8*>(Pp + 64 + 16 * g);   // k=32+8g..

        // ---- PV: O^T[d][q] += VT x P^T (swizzled VT reads, single buffer) ----
        __builtin_amdgcn_s_setprio(1);
        #pragma unroll
        for (int dt = 0; dt < 4; dt++) {
            bf16x8 va0 = *reinterpret_cast<const bf16x8*>(Vb_ + dt * 2048 + c0);
            bf16x8 va1 = *reinterpret_cast<const bf16x8*>(Vb_ + dt * 2048 + c1);
            acc_o[dt] = MFMA(va0, pb0, acc_o[dt]);
            acc_o[dt] = MFMA(va1, pb1, acc_o[dt]);
        }
        __builtin_amdgcn_s_setprio(0);

        // ---- mask for kt+1 ----
        if (has_next && tid < 64) M_lds[(kt + 1) & 1][tid] = sM;
        __syncthreads();   // drains K/DE DMAs; VT reads done for next V-DMA
    }

    // ---- epilogue: O^T -> LDS transpose (over K+VT+DE region) -> out ----
    float inv = 1.0f / l_run;
    float (*OT)[68] = reinterpret_cast<float (*)[68]>(smem);
    #pragma unroll
    for (int dt = 0; dt < 4; dt++)
        #pragma unroll
        for (int r = 0; r < 4; r++)
            OT[16 * w + li][16 * dt + 4 * g + r] = acc_o[dt][r] * inv;
    __syncthreads();
    {
        int q = tid >> 2, seg = tid & 3;
        float* gout = out + ((size_t)(b * 1024 + L0 + q)) * 1024 + h * 64 + 16 * seg;
        #pragma unroll
        for (int j = 0; j < 4; ++j)
            *reinterpret_cast<float4*>(gout + 4 * j) =
                *reinterpret_cast<const float4*>(&OT[q][16 * seg + 4 * j]);
    }
}

// ---------------------------------------------------------------------------
extern "C" void kernel_launch(void* const* d_in, const int* in_sizes, int n_in,
                              void* d_out, int out_size, void* d_ws, size_t ws_size,
                              hipStream_t stream) {
    const float* X   = (const float*)d_in[0];
    const float* msk = (const float*)d_in[1];
    const float* Wq  = (const float*)d_in[2];
    const float* bq  = (const float*)d_in[3];
    const float* Wk  = (const float*)d_in[4];
    const float* bk  = (const float*)d_in[5];
    const float* Wv  = (const float*)d_in[6];
    const float* bv  = (const float*)d_in[7];
    const float* DE  = (const float*)d_in[8];
    float* out = (float*)d_out;

    bf16* ws  = (bf16*)d_ws;
    bf16* Xb  = ws;              // 4194304
    bf16* WTb = ws + 4194304;    // 3145728
    bf16* DEb = ws + 7340032;    // 262144
    bf16* Qb  = ws + 7602176;    // 4194304
    bf16* Kb  = ws + 11796480;   // 4194304
    bf16* VTb = ws + 15990784;   // 4194304

    prep_convert<<<4352, 256, 0, stream>>>(X, DE, Xb, DEb);
    prep_transpose_w<<<dim3(16, 16, 3), 256, 0, stream>>>(Wq, Wk, Wv, WTb);
    proj_gemm<<<dim3(32, 8, 3), 256, 0, stream>>>(Xb, WTb, bq, bk, bv, Qb, Kb, VTb);
    attn_fused<<<dim3(1024), 256, 0, stream>>>(Qb, Kb, VTb, DEb, msk, out);
}

// Round 10
// 141.513 us; speedup vs baseline: 1.1309x; 1.1309x over previous
//
#include <hip/hip_runtime.h>
#include <hip/hip_bf16.h>

typedef __hip_bfloat16 bf16;
typedef __attribute__((ext_vector_type(8))) short bf16x8;   // 8 bf16 = 4 VGPRs (MFMA A/B frag)
typedef __attribute__((ext_vector_type(4))) float f32x4;    // MFMA C/D frag
typedef __attribute__((ext_vector_type(2))) unsigned int u32x2;

#define MFMA(a, b, c) __builtin_amdgcn_mfma_f32_16x16x32_bf16((a), (b), (c), 0, 0, 0)

static __device__ __forceinline__ float bf2f(bf16 b) { return __bfloat162float(b); }

// Packed f32->bf16 (truncation) via single v_perm_b32 (passed r7/r8).
static __device__ __forceinline__ unsigned pk2(float a, float b) {
    return __builtin_amdgcn_perm(__builtin_bit_cast(unsigned, b),
                                 __builtin_bit_cast(unsigned, a), 0x07060302u);
}

// Async global->LDS DMA, 16B per lane. LDS dest = wave-uniform base + lane*16.
static __device__ __forceinline__ void gload16(const void* g, void* l) {
    __builtin_amdgcn_global_load_lds(
        (const __attribute__((address_space(1))) void*)g,
        (__attribute__((address_space(3))) void*)l, 16, 0, 0);
}

static __device__ __forceinline__ float quad_max(float x) {
    x = fmaxf(x, __shfl_xor(x, 16));
    x = fmaxf(x, __shfl_xor(x, 32));
    return x;
}
static __device__ __forceinline__ float quad_sum(float x) {
    x += __shfl_xor(x, 16);
    x += __shfl_xor(x, 32);
    return x;
}

// ---------------------------------------------------------------------------
// Phase 0a: convert hidden_states (4096x1024) and dist_emb (4095x64) to bf16
// ---------------------------------------------------------------------------
__global__ void prep_convert(const float* __restrict__ X, const float* __restrict__ DE,
                             bf16* __restrict__ Xb, bf16* __restrict__ DEb) {
    int i = blockIdx.x * blockDim.x + threadIdx.x;
    if (i < 1048576) {
        float4 v = reinterpret_cast<const float4*>(X)[i];
        bf16* d = Xb + 4 * i;
        d[0] = __float2bfloat16(v.x); d[1] = __float2bfloat16(v.y);
        d[2] = __float2bfloat16(v.z); d[3] = __float2bfloat16(v.w);
    } else {
        int j = i - 1048576;
        if (j < 65520) {
            float4 v = reinterpret_cast<const float4*>(DE)[j];
            bf16* d = DEb + 4 * j;
            d[0] = __float2bfloat16(v.x); d[1] = __float2bfloat16(v.y);
            d[2] = __float2bfloat16(v.z); d[3] = __float2bfloat16(v.w);
        }
    }
}

// ---------------------------------------------------------------------------
// Phase 0b: transpose Wq/Wk/Wv (1024x1024 f32, [in][out]) -> WT bf16 [out][in]
// ---------------------------------------------------------------------------
__global__ void prep_transpose_w(const float* __restrict__ Wq, const float* __restrict__ Wk,
                                 const float* __restrict__ Wv, bf16* __restrict__ WTb) {
    const float* W = (blockIdx.z == 0) ? Wq : (blockIdx.z == 1) ? Wk : Wv;
    bf16* WT = WTb + (size_t)blockIdx.z * (1024u * 1024u);
    __shared__ float t[64][65];
    int tid = threadIdx.x;
    int col = tid & 63;
    int r4 = tid >> 6;
    int i0 = blockIdx.x * 64, o0 = blockIdx.y * 64;
    for (int it = 0; it < 16; ++it) {
        int row = it * 4 + r4;
        t[row][col] = W[(size_t)(i0 + row) * 1024 + o0 + col];
    }
    __syncthreads();
    for (int it = 0; it < 16; ++it) {
        int row = it * 4 + r4;
        WT[(size_t)(o0 + row) * 1024 + i0 + col] = __float2bfloat16(t[col][row]);
    }
}

// ---------------------------------------------------------------------------
// Phase 1: QKV projection GEMM (unchanged — passed).
// ---------------------------------------------------------------------------
__global__ __launch_bounds__(256, 2) void proj_gemm(
    const bf16* __restrict__ Xb, const bf16* __restrict__ WTb,
    const float* __restrict__ bq, const float* __restrict__ bk, const float* __restrict__ bv,
    bf16* __restrict__ Qb, bf16* __restrict__ Kb, bf16* __restrict__ VTb) {
    int proj = blockIdx.z;
    const bf16* W = WTb + (size_t)proj * (1024u * 1024u);
    const float* bias = (proj == 0) ? bq : (proj == 1) ? bk : bv;

    __shared__ bf16 XT[128][72];
    __shared__ bf16 WTt[128][72];

    int tid = threadIdx.x;
    int w = tid >> 6, lane = tid & 63, g = lane >> 4, li = lane & 15;
    int wr = w >> 1, wc = w & 1;
    int m0 = blockIdx.x * 128, n0 = blockIdx.y * 128;

    f32x4 acc[4][4];
    for (int mt = 0; mt < 4; mt++)
        for (int nt = 0; nt < 4; nt++) acc[mt][nt] = {0.f, 0.f, 0.f, 0.f};

    for (int ks = 0; ks < 16; ++ks) {
        for (int it = 0; it < 4; ++it) {
            int idx = tid + 256 * it;
            int row = idx >> 3, c = (idx & 7) * 8;
            *reinterpret_cast<bf16x8*>(&XT[row][c]) =
                *reinterpret_cast<const bf16x8*>(Xb + (size_t)(m0 + row) * 1024 + ks * 64 + c);
            *reinterpret_cast<bf16x8*>(&WTt[row][c]) =
                *reinterpret_cast<const bf16x8*>(W + (size_t)(n0 + row) * 1024 + ks * 64 + c);
        }
        __syncthreads();
        for (int kk = 0; kk < 2; ++kk) {
            bf16x8 af[4], bfr[4];
            for (int mt = 0; mt < 4; mt++)
                af[mt] = *reinterpret_cast<const bf16x8*>(&XT[64 * wr + 16 * mt + li][32 * kk + 8 * g]);
            for (int nt = 0; nt < 4; nt++)
                bfr[nt] = *reinterpret_cast<const bf16x8*>(&WTt[64 * wc + 16 * nt + li][32 * kk + 8 * g]);
            for (int mt = 0; mt < 4; mt++)
                for (int nt = 0; nt < 4; nt++)
                    acc[mt][nt] = MFMA(af[mt], bfr[nt], acc[mt][nt]);
        }
        __syncthreads();
    }

    for (int mt = 0; mt < 4; mt++)
        for (int nt = 0; nt < 4; nt++) {
            int n = n0 + 64 * wc + 16 * nt + li;
            int h = n >> 6, d = n & 63;
            float bv_ = bias[n];
            for (int r = 0; r < 4; r++) {
                int m = m0 + 64 * wr + 16 * mt + 4 * g + r;
                int b = m >> 10, s = m & 1023;
                bf16 o = __float2bfloat16(acc[mt][nt][r] + bv_);
                if (proj == 0)      Qb[((size_t)(b * 16 + h) * 1024 + s) * 64 + d] = o;
                else if (proj == 1) Kb[((size_t)(b * 16 + h) * 1024 + s) * 64 + d] = o;
                else                VTb[((size_t)(b * 16 + h) * 64 + d) * 1024 + s] = o;
            }
        }
}

// ---------------------------------------------------------------------------
// Phase 2: fused attention v10 — 8-wave (512-thread) blocks, 128 Q-rows each,
// grid 512 (2/CU balanced -> 16 waves/CU). DE window 192 rows (mod-192
// circular, 64-aligned). KD pitch 296, split: wave w<4 -> group 3-w cols
// [0,80); w>=4 -> group 7-w cols [64,144) (overlap identical). QD pitch 168.
// ---------------------------------------------------------------------------
__global__ __launch_bounds__(512, 4) void attn_fused(
    const bf16* __restrict__ Qg, const bf16* __restrict__ Kg,
    const bf16* __restrict__ VTg, const bf16* __restrict__ DEb,
    const float* __restrict__ mask, float* __restrict__ out) {
    const int S = 1024, D = 64;
    const float C8 = 0.18033688011112042f;   // log2(e)/8
    int p_ = blockIdx.x;
    int idx = p_ >> 3;
    int bh = (p_ & 7) * 8 + (idx >> 3);      // 8 bh per XCD
    int qb = idx & 7;
    int b = bh >> 4, h = bh & 15;
    int L0 = qb * 128;

    int tid = threadIdx.x;
    int w = tid >> 6, lane = tid & 63, g = lane >> 4, li = lane & 15;

    // LDS (81664 B):
    //  K  [64][128B] lin+swz   @ 0      (8192)
    //  VT [64][128B] lin+swz   @ 8192   (8192)  single buffer
    //  DE [192][128B] lin+swz  @ 16384  (24576) circular, 64-row aligned wrap
    //  QD [8 waves][16 x 168B] @ 40960  (21504) (P overlays per-wave)
    //  KD [64 x 296B]          @ 62464  (18944)
    //  M  bf16[2][64]          @ 81408  (256)
    __shared__ __align__(16) char smem[81664];
    bf16 (*Mb)[64] = reinterpret_cast<bf16(*)[64]>(smem + 81408);

    const char* Kh = (const char*)(Kg + (size_t)bh * S * D);
    const char* Vh = (const char*)(VTg + (size_t)bh * D * S);
    const char* DEc = (const char*)DEb;
    const float* maskb = mask + (size_t)b * S;

    // lane-constant swizzled read cols
    int sw = (li & 7) << 4;
    int c0 = (16 * g) ^ sw;
    int c1 = (64 + 16 * g) ^ sw;
    const char* KbL = smem + li * 128;                      // + nt*2048 + c
    int gsel = (w < 4) ? (3 - w) : (7 - w);
    const char* KaL = smem + (16 * gsel + li) * 128;
    const char* Vb_ = smem + 8192 + li * 128;               // + dt*2048 + c
    const char* Db_ = smem + 16384;                         // + phys*128 + c

    // stager constants (inverse-swizzled source, linear dest)
    int srow = tid >> 3;                       // 0..63
    int sc = 16 * ((lane & 7) ^ (lane >> 3));

    // Q frags (B-operand: col li <-> Q row 16w+li)
    bf16x8 qa0, qa1;
    {
        const bf16* qrow = Qg + (size_t)bh * S * D + (size_t)(L0 + 16 * w + li) * D;
        qa0 = *reinterpret_cast<const bf16x8*>(qrow + 8 * g);
        qa1 = *reinterpret_cast<const bf16x8*>(qrow + 32 + 8 * g);
    }

    // kt-invariant QD/KD/P pointers
    const char* qdb = smem + 40960 + 2688 * w + 170 * li - 8 * g;   // + 126-32nt-2r
    const char* kdb = smem + 62464 + 1176 * g + 32 * w + 2 * li + 30; // + 4736nt+294r
    char* qsp = smem + 40960 + 2688 * w + 168 * li + 8 * g;         // + 32jt
    char* ksp = smem + 62464 + 296 * (16 * gsel + li) + ((w < 4) ? 0 : 128) + 8 * g; // + 32jt
    char* Pp  = smem + 40960 + 2688 * w + 144 * li;                 // overlay on QD[w]

    // Prologue: DMA K(0), VT(0), DE 192-row window, mask(0)
    int de00 = L0 + 1984;
    int jb = de00 % 192;                      // in {0,64,128}
    {
        gload16(Kh + (size_t)srow * 128 + sc, smem + w * 1024);
        gload16(Vh + (size_t)srow * 2048 + sc, smem + 8192 + w * 1024);
        #pragma unroll
        for (int c = 0; c < 3; ++c) {
            int pb = jb + 64 * c; if (pb >= 192) pb -= 192;
            gload16(DEc + (size_t)(de00 + 64 * c + srow) * 128 + sc,
                    smem + 16384 + pb * 128 + w * 1024);
        }
        if (tid < 64) Mb[0][tid] = __float2bfloat16(maskb[tid]);
    }

    f32x4 acc_o[4];
    for (int dt = 0; dt < 4; dt++) acc_o[dt] = {0.f, 0.f, 0.f, 0.f};
    float m_run = -1e30f, l_run = 0.f;

    __syncthreads();   // drains DMAs + mask write

    for (int kt = 0; kt < 16; ++kt) {
        int r0 = kt * 64;
        bool has_next = (kt < 15);
        int jbw = jb + 16 * w;

        // ---- V(kt) DMA (kt>0): prior VT reads done at barrier2(kt-1);
        //      flies during Phase B, drained at barrier1 ----
        if (kt) {
            gload16(Vh + (size_t)srow * 2048 + (size_t)r0 * 2 + sc, smem + 8192 + w * 1024);
        }

        // ---- Phase B: swapped QK^T + QD/KD production ----
        __builtin_amdgcn_s_setprio(1);
        f32x4 s_acc[4];
        #pragma unroll
        for (int nt = 0; nt < 4; ++nt) {
            bf16x8 kb0 = *reinterpret_cast<const bf16x8*>(KbL + nt * 2048 + c0);
            bf16x8 kb1 = *reinterpret_cast<const bf16x8*>(KbL + nt * 2048 + c1);
            f32x4 z = {0.f, 0.f, 0.f, 0.f};
            z = MFMA(kb0, qa0, z);     // S^T[k=16nt+4g+r][q=16w+li]
            z = MFMA(kb1, qa1, z);
            s_acc[nt] = z;
        }
        {
            bf16x8 ka0 = *reinterpret_cast<const bf16x8*>(KaL + c0);
            bf16x8 ka1 = *reinterpret_cast<const bf16x8*>(KaL + c1);
            #pragma unroll
            for (int jt = 0; jt < 5; ++jt) {
                int x = jbw + 16 * jt + li;
                if (x >= 192) x -= 192;
                const char* dp = Db_ + x * 128;
                bf16x8 d0 = *reinterpret_cast<const bf16x8*>(dp + c0);
                bf16x8 d1 = *reinterpret_cast<const bf16x8*>(dp + c1);
                f32x4 aq = {0.f, 0.f, 0.f, 0.f};
                aq = MFMA(d0, qa0, aq);    // QD^T[j=16w+16jt+4g+r][q]
                aq = MFMA(d1, qa1, aq);
                f32x4 ak = {0.f, 0.f, 0.f, 0.f};
                ak = MFMA(d0, ka0, ak);    // KD^T[j][k=16gsel+li]
                ak = MFMA(d1, ka1, ak);
                u32x2 uq = {pk2(aq[0], aq[1]), pk2(aq[2], aq[3])};
                *reinterpret_cast<u32x2*>(qsp + 32 * jt) = uq;
                u32x2 uk = {pk2(ak[0], ak[1]), pk2(ak[2], ak[3])};
                *reinterpret_cast<u32x2*>(ksp + 32 * jt) = uk;
            }
        }
        __builtin_amdgcn_s_setprio(0);
        __syncthreads();   // QD/KD visible; K/DE reads done; V(kt) landed

        // ---- issue K/DE(kt+1) DMAs (fly under Phase C+PV, drain barrier2) ----
        float sM;
        if (has_next) {
            int r0n = r0 + 64;
            int dlo = de00 - 64 * (kt + 1);
            int jbN = (jb >= 64) ? jb - 64 : jb + 128;
            gload16(Kh + (size_t)(r0n + srow) * 128 + sc, smem + w * 1024);
            gload16(DEc + (size_t)(dlo + srow) * 128 + sc,
                    smem + 16384 + jbN * 128 + w * 1024);
            if (tid < 64) sM = maskb[r0n + tid];
            jb = jbN;
        }

        // ---- Phase C: gather + bias + lane-local softmax (scale folded) ----
        float u[4][4];
        float lmax = -1e30f;
        #pragma unroll
        for (int nt = 0; nt < 4; ++nt) {
            unsigned long long mraw =
                *reinterpret_cast<const unsigned long long*>(&Mb[kt & 1][16 * nt + 4 * g]);
            #pragma unroll
            for (int r = 0; r < 4; ++r) {
                float qd = bf2f(*reinterpret_cast<const bf16*>(qdb + (126 - 32 * nt - 2 * r)));
                float kd = bf2f(*reinterpret_cast<const bf16*>(kdb + (4736 * nt + 294 * r)));
                float mk = __builtin_bit_cast(float,
                    (unsigned)((mraw >> (16 * r)) & 0xffffull) << 16);
                float uu = s_acc[nt][r] + qd + kd;
                uu = __builtin_fmaf(mk, 8.0f, uu);
                u[nt][r] = uu;
                lmax = fmaxf(lmax, uu);
            }
        }
        float tm = quad_max(lmax);
        bool noskip = !__all(tm <= m_run);
        float scl = 1.0f;
        if (noskip) {
            float mnew = fmaxf(m_run, tm);
            scl = exp2f((m_run - mnew) * C8);
            m_run = mnew;
        }
        float nmc = -m_run * C8;
        float pv[4][4];
        #pragma unroll
        for (int nt = 0; nt < 4; ++nt)
            #pragma unroll
            for (int r = 0; r < 4; ++r)
                pv[nt][r] = exp2f(__builtin_fmaf(u[nt][r], C8, nmc));
        float t0 = (pv[0][0] + pv[0][1]) + (pv[0][2] + pv[0][3]);
        float t1 = (pv[1][0] + pv[1][1]) + (pv[1][2] + pv[1][3]);
        float t2 = (pv[2][0] + pv[2][1]) + (pv[2][2] + pv[2][3]);
        float t3 = (pv[3][0] + pv[3][1]) + (pv[3][2] + pv[3][3]);
        float qs = quad_sum((t0 + t1) + (t2 + t3));
        if (noskip) {
            l_run = l_run * scl + qs;
            #pragma unroll
            for (int dt = 0; dt < 4; dt++) acc_o[dt] *= scl;
        } else {
            l_run += qs;
        }

        // ---- P^T -> wave-private LDS (overlay; own QD gathers precede in
        //      program order; no cross-wave QD reads) ----
        #pragma unroll
        for (int nt = 0; nt < 4; ++nt) {
            u32x2 pp = {pk2(pv[nt][0], pv[nt][1]), pk2(pv[nt][2], pv[nt][3])};
            *reinterpret_cast<u32x2*>(Pp + 32 * nt + 8 * g) = pp;
        }
        bf16x8 pb0 = *reinterpret_cast<const bf16x8*>(Pp + 16 * g);
        bf16x8 pb1 = *reinterpret_cast<const bf16x8*>(Pp + 64 + 16 * g);

        // ---- PV: O^T[d][q] += VT x P^T ----
        __builtin_amdgcn_s_setprio(1);
        #pragma unroll
        for (int dt = 0; dt < 4; dt++) {
            bf16x8 va0 = *reinterpret_cast<const bf16x8*>(Vb_ + dt * 2048 + c0);
            bf16x8 va1 = *reinterpret_cast<const bf16x8*>(Vb_ + dt * 2048 + c1);
            acc_o[dt] = MFMA(va0, pb0, acc_o[dt]);
            acc_o[dt] = MFMA(va1, pb1, acc_o[dt]);
        }
        __builtin_amdgcn_s_setprio(0);

        // ---- mask for kt+1 ----
        if (has_next && tid < 64) Mb[(kt + 1) & 1][tid] = __float2bfloat16(sM);
        __syncthreads();   // drains K/DE DMAs; VT reads done for next V-DMA
    }

    // ---- epilogue: O^T -> LDS transpose (over K/VT/DE region) -> out ----
    float inv = 1.0f / l_run;
    float (*OT)[68] = reinterpret_cast<float (*)[68]>(smem);
    #pragma unroll
    for (int dt = 0; dt < 4; dt++)
        #pragma unroll
        for (int r = 0; r < 4; r++)
            OT[16 * w + li][16 * dt + 4 * g + r] = acc_o[dt][r] * inv;
    __syncthreads();
    {
        int q = tid >> 2, seg = tid & 3;
        float* gout = out + ((size_t)(b * 1024 + L0 + q)) * 1024 + h * 64 + 16 * seg;
        #pragma unroll
        for (int j = 0; j < 4; ++j)
            *reinterpret_cast<float4*>(gout + 4 * j) =
                *reinterpret_cast<const float4*>(&OT[q][16 * seg + 4 * j]);
    }
}

// ---------------------------------------------------------------------------
extern "C" void kernel_launch(void* const* d_in, const int* in_sizes, int n_in,
                              void* d_out, int out_size, void* d_ws, size_t ws_size,
                              hipStream_t stream) {
    const float* X   = (const float*)d_in[0];
    const float* msk = (const float*)d_in[1];
    const float* Wq  = (const float*)d_in[2];
    const float* bq  = (const float*)d_in[3];
    const float* Wk  = (const float*)d_in[4];
    const float* bk  = (const float*)d_in[5];
    const float* Wv  = (const float*)d_in[6];
    const float* bv  = (const float*)d_in[7];
    const float* DE  = (const float*)d_in[8];
    float* out = (float*)d_out;

    bf16* ws  = (bf16*)d_ws;
    bf16* Xb  = ws;              // 4194304
    bf16* WTb = ws + 4194304;    // 3145728
    bf16* DEb = ws + 7340032;    // 262144
    bf16* Qb  = ws + 7602176;    // 4194304
    bf16* Kb  = ws + 11796480;   // 4194304
    bf16* VTb = ws + 15990784;   // 4194304

    prep_convert<<<4352, 256, 0, stream>>>(X, DE, Xb, DEb);
    prep_transpose_w<<<dim3(16, 16, 3), 256, 0, stream>>>(Wq, Wk, Wv, WTb);
    proj_gemm<<<dim3(32, 8, 3), 256, 0, stream>>>(Xb, WTb, bq, bk, bv, Qb, Kb, VTb);
    attn_fused<<<512, 512, 0, stream>>>(Qb, Kb, VTb, DEb, msk, out);
}